// Round 6
// baseline (279.854 us; speedup 1.0000x reference)
//
#include <hip/hip_runtime.h>
#include <math.h>

// Problem constants
#define BB   4
#define CC   128
#define HH   64
#define WW   64
#define OUTC 128
#define KK   25     // 5x5 attention taps
#define WLDSF 38400 // 128 c * 25 taps * 12 padded dwords

typedef __attribute__((ext_vector_type(8))) short short8;   // 8 bf16
typedef __attribute__((ext_vector_type(4))) float floatx4;  // MFMA acc

__device__ __forceinline__ unsigned short f32_to_bf16(float v) {
    unsigned int u = __float_as_uint(v);
    u += 0x7fffu + ((u >> 16) & 1u);          // RNE
    return (unsigned short)(u >> 16);
}

// ---------------------------------------------------------------------------
// Kernel 0 (prep):
//  i < 16384:  w2o[o][c] = bf16( sum_r w2[o, c*4+r] )        (o-major)
//  else:       w1tp[c][kk][12] = w1[kk][c][0..8] (pad 9..11): 16B-aligned
//              taps so LDS reads are 2x ds_read_b128 + 1x b32.
// ---------------------------------------------------------------------------
__global__ void prep_kernel(const float* __restrict__ w2,
                            const float* __restrict__ w1,
                            unsigned short* __restrict__ w2o,
                            float* __restrict__ w1tp) {
    int i = blockIdx.x * 256 + threadIdx.x;
    if (i < 16384) {
        int o = i >> 7, c = i & 127;
        const float* p = w2 + o * (4 * CC) + c * 4;
        w2o[o * CC + c] = f32_to_bf16(p[0] + p[1] + p[2] + p[3]);
    } else if (i < 16384 + 38400) {
        int j   = i - 16384;
        int c   = j / 300;
        int rem = j - c * 300;
        int kk  = rem / 12;
        int jj  = rem - kk * 12;
        w1tp[j] = (jj < 9) ? w1[((size_t)kk * CC + c) * 9 + jj] : 0.f;
    }
}

// ---------------------------------------------------------------------------
// Fused kernel: conv1 (3x3) + softmax + local attention + MFMA + 2x2 store.
// grid 256 = (b, h): one full 64-px row per block, 1024 threads (16 waves),
// 1 block/CU (LDS-bound). Weights staged in LDS once per block and read
// WAVE-UNIFORM (broadcast ds_read_b128: 16B, not the 1KB/instr that the
// per-lane VMEM weight streams of rounds 2-4 cost -> their ~80us L1 floor).
//
// __launch_bounds__(1024, 2): VGPR cap 128. ROUND 3+5 LESSON: second-arg 4
// forces a 64-VGPR allocation -> the 25 conv accumulators + phase-C state
// spill to scratch (round 5: 670 MB scratch traffic = the entire 220 us).
// Empirically (rounds 2/4) this code shape allocates ~116 VGPR with cap
// 128 -> no spill, and 1024-thread blocks need <=128 to launch anyway.
//
//  conv1 : lane = px (full row), wave = 8-channel slice. 9 coalesced x
//          loads per channel feed 225 FMA; weights broadcast from LDS.
//          Merge: 25 conflict-free ds-atomics per wave (64 distinct px).
//  softmax: in-register per phase-C thread (redundant, zero barriers).
//  phase C: x windows straight from L1/L2 (rows warm from conv).
//  MFMA  : C[128 o][64 px]: 16 waves = 8(o-tile) x 2(px-half).
// ---------------------------------------------------------------------------
__global__ __launch_bounds__(1024, 2) void fused_kernel(
        const float* __restrict__ x,
        const float* __restrict__ w1tp,
        const unsigned short* __restrict__ w2o,
        const float* __restrict__ b1,
        const float* __restrict__ b2,
        float* __restrict__ out) {
    __shared__ float wlds[WLDSF];               // 153.6 KB (sKT overlays)
    __shared__ float pk[KK * 64];               // logits (6.4 KB)
    unsigned short* sKT = (unsigned short*)wlds; // 64 x 136 bf16 (17.4 KB)

    // XCD swizzle (256 % 8 == 0 -> bijective): 32 consecutive (b,h) per
    // XCD -> neighboring rows (shared x lines h+-2) on the same L2.
    int bid0 = blockIdx.x;
    int bid  = (bid0 & 7) * 32 + (bid0 >> 3);
    int h = bid & 63;
    int b = bid >> 6;
    int t = threadIdx.x;
    int lane = t & 63;

    // ---- stage weights to LDS + init logits with bias ----
    {
        const float4* src = (const float4*)w1tp;
        float4* dst = (float4*)wlds;
        for (int i = t; i < WLDSF / 4; i += 1024) dst[i] = src[i];
        for (int i = t; i < KK * 64; i += 1024) pk[i] = b1[i >> 6];
    }
    __syncthreads();

    // ---- conv1 3x3 SAME: lane = px, wave = 8 channels ----
    int px = lane;
    int wv = t >> 6;                 // 0..15
    float mt = (h > 0) ? 1.f : 0.f, mb = (h < HH - 1) ? 1.f : 0.f;
    float ml = (px > 0) ? 1.f : 0.f, mr = (px < WW - 1) ? 1.f : 0.f;
    int ya = (h > 0) ? h - 1 : 0;
    int yb = (h < HH - 1) ? h + 1 : HH - 1;
    int xl = (px > 0) ? px - 1 : 0;
    int xr = (px < WW - 1) ? px + 1 : WW - 1;

    float acc[KK];
    #pragma unroll
    for (int k = 0; k < KK; ++k) acc[k] = 0.f;

    const float* xb = x + (size_t)b * CC * (HH * WW);
    #pragma unroll 2
    for (int ci = 0; ci < 8; ++ci) {
        int c = wv * 8 + ci;
        const float* xp = xb + (size_t)c * (HH * WW);
        const float* r0 = xp + ya * WW;
        const float* r1 = xp + h  * WW;
        const float* r2 = xp + yb * WW;
        float x00 = r0[xl] * (mt * ml), x01 = r0[px] * mt, x02 = r0[xr] * (mt * mr);
        float x10 = r1[xl] * ml,        x11 = r1[px],      x12 = r1[xr] * mr;
        float x20 = r2[xl] * (mb * ml), x21 = r2[px] * mb, x22 = r2[xr] * (mb * mr);

        const float* wc = wlds + c * 300;        // wave-uniform -> broadcast
        #pragma unroll
        for (int kk = 0; kk < KK; ++kk) {
            float4 wA = *(const float4*)(wc + kk * 12);
            float4 wB = *(const float4*)(wc + kk * 12 + 4);
            float  w8 = wc[kk * 12 + 8];
            acc[kk] += x00 * wA.x + x01 * wA.y + x02 * wA.z
                     + x10 * wA.w + x11 * wB.x + x12 * wB.y
                     + x20 * wB.z + x21 * wB.w + x22 * w8;
        }
    }
    // merge 16 wave-partials (64 distinct px per wave -> conflict-free)
    #pragma unroll
    for (int k = 0; k < KK; ++k)
        atomicAdd(&pk[k * 64 + px], acc[k]);
    __syncthreads();   // conv done: weights dead, sKT region reusable

    // ---- phase C: in-register softmax + attention straight from L1/L2 ----
    // thread = (pp2 = t&31 -> px {2pp2, 2pp2+1}, cw = t>>5 -> 4 channels)
    int pp2 = t & 31, cw = t >> 5;

    float2 lg[KK];
    #pragma unroll
    for (int k = 0; k < KK; ++k) lg[k] = *(const float2*)&pk[k * 64 + 2 * pp2];
    float m0 = -1e30f, m1 = -1e30f;
    #pragma unroll
    for (int k = 0; k < KK; ++k) { m0 = fmaxf(m0, lg[k].x); m1 = fmaxf(m1, lg[k].y); }
    float s0 = 0.f, s1 = 0.f;
    #pragma unroll
    for (int k = 0; k < KK; ++k) {
        lg[k].x = __expf(lg[k].x - m0); s0 += lg[k].x;
        lg[k].y = __expf(lg[k].y - m1); s1 += lg[k].y;
    }
    float i0 = 1.f / s0, i1 = 1.f / s1;
    #pragma unroll
    for (int k = 0; k < KK; ++k) { lg[k].x *= i0; lg[k].y *= i1; }

    // window geometry: 5 rows x 3 float2 loads (even col offsets -> a
    // float2 is fully in-bounds or fully out -> single mask per pair)
    int colg = 2 * pp2 - 2;
    int coff[3]; float cmask[3];
    #pragma unroll
    for (int j = 0; j < 3; ++j) {
        int cg = colg + 2 * j;
        cmask[j] = (cg >= 0 && cg <= WW - 2) ? 1.f : 0.f;
        coff[j]  = min(max(cg, 0), WW - 2);
    }
    int yoff[5]; float msk[15];
    #pragma unroll
    for (int di = 0; di < 5; ++di) {
        int y = h + di - 2;
        float rm = (y >= 0 && y < HH) ? 1.f : 0.f;
        yoff[di] = min(max(y, 0), HH - 1) * WW;
        #pragma unroll
        for (int j = 0; j < 3; ++j) msk[di * 3 + j] = rm * cmask[j];
    }

    #pragma unroll 2
    for (int i4 = 0; i4 < 4; ++i4) {
        int c = i4 * 32 + cw;
        const float* xc = xb + (size_t)c * (HH * WW);
        float2 xv[15];
        #pragma unroll
        for (int di = 0; di < 5; ++di)
            #pragma unroll
            for (int j = 0; j < 3; ++j) {
                float2 v = *(const float2*)(xc + yoff[di] + coff[j]);
                float mm = msk[di * 3 + j];
                xv[di * 3 + j] = make_float2(v.x * mm, v.y * mm);
            }
        float t0 = 0.f, t1 = 0.f;
        #pragma unroll
        for (int di = 0; di < 5; ++di) {
            float2 x01 = xv[di * 3 + 0];
            float2 x23 = xv[di * 3 + 1];
            float2 x45 = xv[di * 3 + 2];
            t0 += lg[di*5+0].x * x01.x + lg[di*5+1].x * x01.y
                + lg[di*5+2].x * x23.x + lg[di*5+3].x * x23.y
                + lg[di*5+4].x * x45.x;
            t1 += lg[di*5+0].y * x01.y + lg[di*5+1].y * x23.x
                + lg[di*5+2].y * x23.y + lg[di*5+3].y * x45.x
                + lg[di*5+4].y * x45.y;
        }
        sKT[(2 * pp2) * 136 + c]     = f32_to_bf16(t0);
        sKT[(2 * pp2 + 1) * 136 + c] = f32_to_bf16(t1);
    }
    __syncthreads();

    // ---- MFMA: C[o][px] = sum_c W2s[o][c] * s[c][px] ----
    // wave = (ot = wv&7 -> o rows [16ot,16ot+16), ph = wv>>3 -> px half)
    int ot = wv & 7, ph = wv >> 3;
    int fpx = lane & 15, quad = lane >> 4;
    floatx4 am[2] = {{0.f,0.f,0.f,0.f},{0.f,0.f,0.f,0.f}};
    #pragma unroll
    for (int ks = 0; ks < 4; ++ks) {
        short8 bf0 = *(const short8*)&sKT[(32*ph      + fpx) * 136 + ks*32 + quad*8];
        short8 bf1 = *(const short8*)&sKT[(32*ph + 16 + fpx) * 136 + ks*32 + quad*8];
        short8 af  = *(const short8*)&w2o[(size_t)(16*ot + fpx) * CC + ks*32 + quad*8];
        am[0] = __builtin_amdgcn_mfma_f32_16x16x32_bf16(af, bf0, am[0], 0, 0, 0);
        am[1] = __builtin_amdgcn_mfma_f32_16x16x32_bf16(af, bf1, am[1], 0, 0, 0);
    }

    // ---- epilogue: D[row=quad*4+reg][col=fpx] + b2, 2x2-replicated write ----
    float* ob = out + (size_t)b * OUTC * (4 * HH * WW);
    int y0 = 2 * h;
    #pragma unroll
    for (int nt = 0; nt < 2; ++nt) {
        #pragma unroll
        for (int reg = 0; reg < 4; ++reg) {
            int o   = 16*ot + quad*4 + reg;
            int pxo = 32*ph + 16*nt + fpx;
            float v = am[nt][reg] + b2[o];
            float2 v2 = make_float2(v, v);
            float* r0p = ob + ((size_t)o * (2*HH) + y0) * (2*WW) + 2*pxo;
            *(float2*)(r0p)        = v2;
            *(float2*)(r0p + 2*WW) = v2;
        }
    }
}

// ---------------------------------------------------------------------------
extern "C" void kernel_launch(void* const* d_in, const int* in_sizes, int n_in,
                              void* d_out, int out_size, void* d_ws, size_t ws_size,
                              hipStream_t stream) {
    const float* x  = (const float*)d_in[0];
    const float* w1 = (const float*)d_in[1];
    const float* b1 = (const float*)d_in[2];
    const float* w2 = (const float*)d_in[3];
    const float* b2 = (const float*)d_in[4];
    float* out = (float*)d_out;

    unsigned short* w2o = (unsigned short*)d_ws;               // 32 KB
    float* w1tp = (float*)(w2o + (size_t)OUTC * CC);           // 153.6 KB

    prep_kernel<<<(16384 + 38400 + 255) / 256, 256, 0, stream>>>(w2, w1, w2o, w1tp);
    fused_kernel<<<BB * HH, 1024, 0, stream>>>(x, w1tp, w2o, b1, b2, out);
}

// Round 7
// 137.947 us; speedup vs baseline: 2.0287x; 2.0287x over previous
//
#include <hip/hip_runtime.h>
#include <math.h>

// Problem constants
#define BB   4
#define CC   128
#define HH   64
#define WW   64
#define OUTC 128
#define KK   25     // 5x5 attention taps
#define WLDSF 38400 // 128 c * 25 taps * 12 padded dwords

typedef __attribute__((ext_vector_type(8))) short short8;   // 8 bf16
typedef __attribute__((ext_vector_type(4))) float floatx4;  // MFMA acc

__device__ __forceinline__ unsigned short f32_to_bf16(float v) {
    unsigned int u = __float_as_uint(v);
    u += 0x7fffu + ((u >> 16) & 1u);          // RNE
    return (unsigned short)(u >> 16);
}

// ---------------------------------------------------------------------------
// Kernel 0 (prep):
//  i < 16384:  w2o[o][c] = bf16( sum_r w2[o, c*4+r] )        (o-major)
//  else:       w1tp[c][kk][12] = w1[kk][c][0..8] (pad 9..11): 16B-aligned
//              taps so LDS reads are 2x ds_read_b128 + 1x b32.
// ---------------------------------------------------------------------------
__global__ void prep_kernel(const float* __restrict__ w2,
                            const float* __restrict__ w1,
                            unsigned short* __restrict__ w2o,
                            float* __restrict__ w1tp) {
    int i = blockIdx.x * 256 + threadIdx.x;
    if (i < 16384) {
        int o = i >> 7, c = i & 127;
        const float* p = w2 + o * (4 * CC) + c * 4;
        w2o[o * CC + c] = f32_to_bf16(p[0] + p[1] + p[2] + p[3]);
    } else if (i < 16384 + 38400) {
        int j   = i - 16384;
        int c   = j / 300;
        int rem = j - c * 300;
        int kk  = rem / 12;
        int jj  = rem - kk * 12;
        w1tp[j] = (jj < 9) ? w1[((size_t)kk * CC + c) * 9 + jj] : 0.f;
    }
}

// ---------------------------------------------------------------------------
// Fused kernel: conv1 (3x3) + softmax + local attention + MFMA + 2x2 store.
// grid 256 = (b, h): one full 64-px row per block, 512 threads (8 waves).
//
// REGISTER-BUDGET MODEL (fitted to rounds 1-6): per-wave total budget
// (arch VGPR + AGPR) = 512 / waves-per-SIMD. A 1024-thread block forces
// 4 waves/SIMD -> 128 total -> arch VGPR squeezed to 64 -> the 25 conv
// accumulators spill (rounds 5/6: 670 MB scratch = the whole 216 us).
// 512-thread block at __launch_bounds__(512,2) -> 2 waves/SIMD -> 256
// total: round 1 measured arch=68, ZERO spill. So: same LDS-broadcast
// design as rounds 5/6, block shape from round 1.
//
// Weights staged in LDS once per block, read WAVE-UNIFORM (broadcast
// ds_read_b128 = 16B/instr, vs the per-lane VMEM weight streams of
// rounds 2-4 whose 1KB/instr L1 return traffic set their ~80us floor).
// LDS: weights 153.6KB + pk 6.4KB = 160.0KB; sKT (17.4KB) overlays the
// dead weight region after conv.
//  conv1 : lane = px (full row), wave = 16-channel slice. 9 coalesced x
//          loads per channel feed 225 FMA; weights broadcast from LDS.
//          Merge: 25 conflict-free ds-atomics per wave (64 distinct px).
//  softmax: in-register per phase-C thread (redundant, zero barriers).
//  phase C: x windows straight from L1/L2 (rows warm from conv).
//  MFMA  : C[128 o][64 px]: 8 waves, wave ot owns o-rows [16ot,16ot+16),
//          4 px-tiles x 4 ks = 16 MFMA, acc = 4x floatx4 (16 AGPRs).
// ---------------------------------------------------------------------------
__global__ __launch_bounds__(512, 2) void fused_kernel(
        const float* __restrict__ x,
        const float* __restrict__ w1tp,
        const unsigned short* __restrict__ w2o,
        const float* __restrict__ b1,
        const float* __restrict__ b2,
        float* __restrict__ out) {
    __shared__ float wlds[WLDSF];               // 153.6 KB (sKT overlays)
    __shared__ float pk[KK * 64];               // logits (6.4 KB)
    unsigned short* sKT = (unsigned short*)wlds; // 64 x 136 bf16 (17.4 KB)

    // XCD swizzle (256 % 8 == 0 -> bijective): 32 consecutive (b,h) per
    // XCD -> neighboring rows (shared x lines h+-2) on the same L2.
    int bid0 = blockIdx.x;
    int bid  = (bid0 & 7) * 32 + (bid0 >> 3);
    int h = bid & 63;
    int b = bid >> 6;
    int t = threadIdx.x;
    int lane = t & 63;
    int wv = t >> 6;                 // 0..7

    // ---- stage weights to LDS + init logits with bias ----
    {
        const float4* src = (const float4*)w1tp;
        float4* dst = (float4*)wlds;
        for (int i = t; i < WLDSF / 4; i += 512) dst[i] = src[i];
        for (int i = t; i < KK * 64; i += 512) pk[i] = b1[i >> 6];
    }
    __syncthreads();

    // ---- conv1 3x3 SAME: lane = px, wave = 16 channels ----
    int px = lane;
    float mt = (h > 0) ? 1.f : 0.f, mb = (h < HH - 1) ? 1.f : 0.f;
    float ml = (px > 0) ? 1.f : 0.f, mr = (px < WW - 1) ? 1.f : 0.f;
    int ya = (h > 0) ? h - 1 : 0;
    int yb = (h < HH - 1) ? h + 1 : HH - 1;
    int xl = (px > 0) ? px - 1 : 0;
    int xr = (px < WW - 1) ? px + 1 : WW - 1;

    float acc[KK];
    #pragma unroll
    for (int k = 0; k < KK; ++k) acc[k] = 0.f;

    const float* xb = x + (size_t)b * CC * (HH * WW);
    #pragma unroll 2
    for (int ci = 0; ci < 16; ++ci) {
        int c = wv * 16 + ci;
        const float* xp = xb + (size_t)c * (HH * WW);
        const float* r0 = xp + ya * WW;
        const float* r1 = xp + h  * WW;
        const float* r2 = xp + yb * WW;
        float x00 = r0[xl] * (mt * ml), x01 = r0[px] * mt, x02 = r0[xr] * (mt * mr);
        float x10 = r1[xl] * ml,        x11 = r1[px],      x12 = r1[xr] * mr;
        float x20 = r2[xl] * (mb * ml), x21 = r2[px] * mb, x22 = r2[xr] * (mb * mr);

        const float* wc = wlds + c * 300;        // wave-uniform -> broadcast
        #pragma unroll
        for (int kk = 0; kk < KK; ++kk) {
            float4 wA = *(const float4*)(wc + kk * 12);
            float4 wB = *(const float4*)(wc + kk * 12 + 4);
            float  w8 = wc[kk * 12 + 8];
            acc[kk] += x00 * wA.x + x01 * wA.y + x02 * wA.z
                     + x10 * wA.w + x11 * wB.x + x12 * wB.y
                     + x20 * wB.z + x21 * wB.w + x22 * w8;
        }
    }
    // merge 8 wave-partials (64 distinct px per wave -> conflict-free)
    #pragma unroll
    for (int k = 0; k < KK; ++k)
        atomicAdd(&pk[k * 64 + px], acc[k]);
    __syncthreads();   // conv done: weights dead, sKT region reusable

    // ---- phase C: in-register softmax + attention straight from L1/L2 ----
    // thread = (pp2 = t&31 -> px {2pp2, 2pp2+1}, cw = t>>5 -> 8 channels)
    int pp2 = t & 31, cw = t >> 5;

    float2 lg[KK];
    #pragma unroll
    for (int k = 0; k < KK; ++k) lg[k] = *(const float2*)&pk[k * 64 + 2 * pp2];
    float m0 = -1e30f, m1 = -1e30f;
    #pragma unroll
    for (int k = 0; k < KK; ++k) { m0 = fmaxf(m0, lg[k].x); m1 = fmaxf(m1, lg[k].y); }
    float s0 = 0.f, s1 = 0.f;
    #pragma unroll
    for (int k = 0; k < KK; ++k) {
        lg[k].x = __expf(lg[k].x - m0); s0 += lg[k].x;
        lg[k].y = __expf(lg[k].y - m1); s1 += lg[k].y;
    }
    float i0 = 1.f / s0, i1 = 1.f / s1;
    #pragma unroll
    for (int k = 0; k < KK; ++k) { lg[k].x *= i0; lg[k].y *= i1; }

    // window geometry: 5 rows x 3 float2 loads (even col offsets -> a
    // float2 is fully in-bounds or fully out -> single mask per pair)
    int colg = 2 * pp2 - 2;
    int coff[3]; float cmask[3];
    #pragma unroll
    for (int j = 0; j < 3; ++j) {
        int cg = colg + 2 * j;
        cmask[j] = (cg >= 0 && cg <= WW - 2) ? 1.f : 0.f;
        coff[j]  = min(max(cg, 0), WW - 2);
    }
    int yoff[5]; float msk[15];
    #pragma unroll
    for (int di = 0; di < 5; ++di) {
        int y = h + di - 2;
        float rm = (y >= 0 && y < HH) ? 1.f : 0.f;
        yoff[di] = min(max(y, 0), HH - 1) * WW;
        #pragma unroll
        for (int j = 0; j < 3; ++j) msk[di * 3 + j] = rm * cmask[j];
    }

    #pragma unroll 2
    for (int i8 = 0; i8 < 8; ++i8) {
        int c = i8 * 16 + cw;
        const float* xc = xb + (size_t)c * (HH * WW);
        float2 xv[15];
        #pragma unroll
        for (int di = 0; di < 5; ++di)
            #pragma unroll
            for (int j = 0; j < 3; ++j) {
                float2 v = *(const float2*)(xc + yoff[di] + coff[j]);
                float mm = msk[di * 3 + j];
                xv[di * 3 + j] = make_float2(v.x * mm, v.y * mm);
            }
        float t0 = 0.f, t1 = 0.f;
        #pragma unroll
        for (int di = 0; di < 5; ++di) {
            float2 x01 = xv[di * 3 + 0];
            float2 x23 = xv[di * 3 + 1];
            float2 x45 = xv[di * 3 + 2];
            t0 += lg[di*5+0].x * x01.x + lg[di*5+1].x * x01.y
                + lg[di*5+2].x * x23.x + lg[di*5+3].x * x23.y
                + lg[di*5+4].x * x45.x;
            t1 += lg[di*5+0].y * x01.y + lg[di*5+1].y * x23.x
                + lg[di*5+2].y * x23.y + lg[di*5+3].y * x45.x
                + lg[di*5+4].y * x45.y;
        }
        sKT[(2 * pp2) * 136 + c]     = f32_to_bf16(t0);
        sKT[(2 * pp2 + 1) * 136 + c] = f32_to_bf16(t1);
    }
    __syncthreads();

    // ---- MFMA: C[o][px] = sum_c W2s[o][c] * s[c][px] ----
    // wave ot = wv owns o rows [16ot,16ot+16); 4 px-tiles of 16.
    int fpx = lane & 15, quad = lane >> 4;
    floatx4 am[4] = {{0.f,0.f,0.f,0.f},{0.f,0.f,0.f,0.f},
                     {0.f,0.f,0.f,0.f},{0.f,0.f,0.f,0.f}};
    #pragma unroll
    for (int ks = 0; ks < 4; ++ks) {
        short8 af = *(const short8*)&w2o[(size_t)(16*wv + fpx) * CC + ks*32 + quad*8];
        #pragma unroll
        for (int nt = 0; nt < 4; ++nt) {
            short8 bf = *(const short8*)&sKT[(16*nt + fpx) * 136 + ks*32 + quad*8];
            am[nt] = __builtin_amdgcn_mfma_f32_16x16x32_bf16(af, bf, am[nt], 0, 0, 0);
        }
    }

    // ---- epilogue: D[row=quad*4+reg][col=fpx] + b2, 2x2-replicated write ----
    float* ob = out + (size_t)b * OUTC * (4 * HH * WW);
    int y0 = 2 * h;
    #pragma unroll
    for (int nt = 0; nt < 4; ++nt) {
        #pragma unroll
        for (int reg = 0; reg < 4; ++reg) {
            int o   = 16*wv + quad*4 + reg;
            int pxo = 16*nt + fpx;
            float v = am[nt][reg] + b2[o];
            float2 v2 = make_float2(v, v);
            float* r0p = ob + ((size_t)o * (2*HH) + y0) * (2*WW) + 2*pxo;
            *(float2*)(r0p)        = v2;
            *(float2*)(r0p + 2*WW) = v2;
        }
    }
}

// ---------------------------------------------------------------------------
extern "C" void kernel_launch(void* const* d_in, const int* in_sizes, int n_in,
                              void* d_out, int out_size, void* d_ws, size_t ws_size,
                              hipStream_t stream) {
    const float* x  = (const float*)d_in[0];
    const float* w1 = (const float*)d_in[1];
    const float* b1 = (const float*)d_in[2];
    const float* w2 = (const float*)d_in[3];
    const float* b2 = (const float*)d_in[4];
    float* out = (float*)d_out;

    unsigned short* w2o = (unsigned short*)d_ws;               // 32 KB
    float* w1tp = (float*)(w2o + (size_t)OUTC * CC);           // 153.6 KB

    prep_kernel<<<(16384 + 38400 + 255) / 256, 256, 0, stream>>>(w2, w1, w2o, w1tp);
    fused_kernel<<<BB * HH, 512, 0, stream>>>(x, w1tp, w2o, b1, b2, out);
}

// Round 8
// 102.075 us; speedup vs baseline: 2.7417x; 1.3514x over previous
//
#include <hip/hip_runtime.h>
#include <math.h>

// Problem constants
#define BB   4
#define CC   128
#define HH   64
#define WW   64
#define OUTC 128
#define KK   25     // 5x5 attention taps

typedef __attribute__((ext_vector_type(8))) short short8;   // 8 bf16
typedef __attribute__((ext_vector_type(4))) float floatx4;  // MFMA acc

__device__ __forceinline__ unsigned short f32_to_bf16(float v) {
    unsigned int u = __float_as_uint(v);
    u += 0x7fffu + ((u >> 16) & 1u);          // RNE
    return (unsigned short)(u >> 16);
}
__device__ __forceinline__ float bf16_to_f32(unsigned short h) {
    return __uint_as_float(((unsigned int)h) << 16);
}

// ---------------------------------------------------------------------------
// Kernel 0 (prep):
//  i < 16384:  w2o[o][c] = bf16( sum_r w2[o, c*4+r] )   (o-major, MFMA A)
//  else:       w1f = conv1 weights pre-packed in MFMA A-fragment lane order,
//              bf16 hi/lo split:
//              w1f[((((wt*9+dydx)*2+mt)*4+ks)*64+lane)*8+i8]
//                = split_wt( w1[kk= mt*16+(lane&15)][c= ks*32+(lane>>4)*8+i8]
//                            [dy=dydx/3][dx=dydx%3] ),  0 for kk>=25.
//              -> each conv MFMA's A operand is ONE fully-coalesced 1KB load.
// ---------------------------------------------------------------------------
__global__ void prep_kernel(const float* __restrict__ w2,
                            const float* __restrict__ w1,
                            unsigned short* __restrict__ w2o,
                            unsigned short* __restrict__ w1f) {
    int i = blockIdx.x * 256 + threadIdx.x;
    if (i < 16384) {
        int o = i >> 7, c = i & 127;
        const float* p = w2 + o * (4 * CC) + c * 4;
        w2o[o * CC + c] = f32_to_bf16(p[0] + p[1] + p[2] + p[3]);
    } else {
        int f = i - 16384;            // 0..73727
        int i8 = f & 7;  int rest = f >> 3;
        int lane = rest & 63; rest >>= 6;
        int ks = rest & 3;  rest >>= 2;
        int mt = rest & 1;  rest >>= 1;
        int dydx = rest % 9;
        int wt   = rest / 9;          // 0 = hi, 1 = lo
        int kk = mt * 16 + (lane & 15);
        int c  = ks * 32 + (lane >> 4) * 8 + i8;
        unsigned short o16 = 0;
        if (kk < KK) {
            float v = w1[(size_t)(kk * CC + c) * 9 + dydx];
            unsigned short hi = f32_to_bf16(v);
            o16 = wt ? f32_to_bf16(v - bf16_to_f32(hi)) : hi;
        }
        w1f[f] = o16;
    }
}

// ---------------------------------------------------------------------------
// Fused kernel: conv1-as-MFMA + softmax + local attention + MFMA + 2x2 store.
// grid 256 = (b, h): one 64-px row per block, 512 threads (8 waves).
//
// ROUND 2-7 LESSON (the ~85us wall): delivering conv weights by per-wave
// instructions costs ~1 wave-inst per ~3 FMA no matter the path — per-lane
// VMEM streams (1KB L1-return/inst, r2/r4) or LDS broadcast (full-wave
// issue ~10cyc even for uniform addr, r7: 9600 ds_reads/CU = ~40us). MFMA
// breaks the economics: one B-frag read feeds 8192 MACs. So conv1 = 9
// shifted GEMMs (M=32pad, N=64, K=128) on the matrix pipe.
//
// Precision: bf16 hi/lo split (x=xh+xl, w=wh+wl; 3 terms hh+hl+lh, dropped
// ll ~2^-18) -> logits f32-accurate -> absmax unchanged.
//
//  stage : xs_hi/xs_lo[row 0..2][col j 0..67][c^swz] bf16, j = xcol+2,
//          borders ZERO-FILLED (no masks in MFMA path). swz=(j&15)<<3
//          preserves 16B c-blocks, spreads the 256B px-stride across banks.
//  conv  : wave (mt,nt) owns D[kk 16][px 16]; 9(dydx) x 4(ks) x 3 terms =
//          108 MFMA, A from global (coalesced, L2-hot), B from xs.
//  phase C / softmax / MFMA2 / epilogue: r7 code verbatim (5x proven).
// LDS: xs 104.4KB + pk 6.4KB + blds = 111KB; sKT overlays xs after conv.
// __launch_bounds__(512,2): 256-reg budget, proven no-spill shape (r1/r7).
// ---------------------------------------------------------------------------
__global__ __launch_bounds__(512, 2) void fused_kernel(
        const float* __restrict__ x,
        const unsigned short* __restrict__ w1f,
        const unsigned short* __restrict__ w2o,
        const float* __restrict__ b1,
        const float* __restrict__ b2,
        float* __restrict__ out) {
    __shared__ unsigned short xs_hi[3 * 68 * 128];   // 52224 B
    __shared__ unsigned short xs_lo[3 * 68 * 128];   // 52224 B
    __shared__ float pk[KK * 64];                    // logits (6.4 KB)
    __shared__ float blds[32];
    unsigned short* sKT = xs_hi;     // 64 x 136 bf16 overlay (17.4 KB)

    // XCD swizzle (256 % 8 == 0 -> bijective)
    int bid0 = blockIdx.x;
    int bid  = (bid0 & 7) * 32 + (bid0 >> 3);
    int h = bid & 63;
    int b = bid >> 6;
    int t = threadIdx.x;
    int lane = t & 63;
    int wv = t >> 6;                 // 0..7

    const float* xb = x + (size_t)b * CC * (HH * WW);

    // ---- stage x rows h-1..h+1 transposed+swizzled, bf16 hi/lo ----
    if (t < KK) blds[t] = b1[t];
    {
        int j = lane + 2;                        // staged col (xcol = j-2)
        int swz = (j & 15) << 3;
        for (int ci = 0; ci < 16; ++ci) {
            int c  = wv * 16 + ci;
            int cs = c ^ swz;
            const float* xc = xb + (size_t)c * (HH * WW);
            #pragma unroll
            for (int r = 0; r < 3; ++r) {
                int y = h - 1 + r;
                float v = (y >= 0 && y < HH) ? xc[y * WW + lane] : 0.f;
                unsigned short hi = f32_to_bf16(v);
                unsigned short lo = f32_to_bf16(v - bf16_to_f32(hi));
                xs_hi[(r * 68 + j) * 128 + cs] = hi;
                xs_lo[(r * 68 + j) * 128 + cs] = lo;
            }
        }
        for (int i = t; i < 3 * 4 * 128; i += 512) {   // zero cols 0,1,66,67
            int c = i & 127; int rem = i >> 7;
            int jj = rem & 3; int r = rem >> 2;
            int j2 = (jj < 2) ? jj : 64 + jj;
            int cs2 = c ^ ((j2 & 15) << 3);
            xs_hi[(r * 68 + j2) * 128 + cs2] = 0;
            xs_lo[(r * 68 + j2) * 128 + cs2] = 0;
        }
    }
    __syncthreads();

    // ---- conv1 via MFMA: D[kk][px] = sum_{c,dy,dx} w1*x ----
    int fpx = lane & 15, quad = lane >> 4;
    int mt = wv & 1, ntw = wv >> 1;
    int pxb = ntw * 16 + fpx;
    floatx4 acc = {0.f, 0.f, 0.f, 0.f};
    for (int dydx = 0; dydx < 9; ++dydx) {
        int r   = dydx / 3;                      // dy index = staged row
        int dxm = dydx - 3 * r;                  // dx index 0..2
        int j   = pxb + dxm + 1;                 // staged col = px+dx-1+2
        int rowbase = (r * 68 + j) * 128;
        int swz = (j & 15) << 3;
        const unsigned short* whb = w1f + (dydx * 2 + mt) * 2048 + lane * 8;
        #pragma unroll
        for (int ks = 0; ks < 4; ++ks) {
            int cb = (ks * 32 + quad * 8) ^ swz;
            short8 Ah = *(const short8*)(whb + ks * 512);
            short8 Al = *(const short8*)(whb + 36864 + ks * 512);
            short8 Bh = *(const short8*)&xs_hi[rowbase + cb];
            short8 Bl = *(const short8*)&xs_lo[rowbase + cb];
            acc = __builtin_amdgcn_mfma_f32_16x16x32_bf16(Ah, Bh, acc, 0, 0, 0);
            acc = __builtin_amdgcn_mfma_f32_16x16x32_bf16(Ah, Bl, acc, 0, 0, 0);
            acc = __builtin_amdgcn_mfma_f32_16x16x32_bf16(Al, Bh, acc, 0, 0, 0);
        }
    }
    #pragma unroll
    for (int reg = 0; reg < 4; ++reg) {          // D row = quad*4+reg
        int kk = mt * 16 + quad * 4 + reg;
        if (kk < KK) pk[kk * 64 + pxb] = acc[reg] + blds[kk];
    }
    __syncthreads();   // pk ready; xs dead -> sKT region reusable

    // ---- phase C: in-register softmax + attention straight from L1/L2 ----
    // thread = (pp2 = t&31 -> px {2pp2, 2pp2+1}, cw = t>>5 -> 8 channels)
    int pp2 = t & 31, cw = t >> 5;

    float2 lg[KK];
    #pragma unroll
    for (int k = 0; k < KK; ++k) lg[k] = *(const float2*)&pk[k * 64 + 2 * pp2];
    float m0 = -1e30f, m1 = -1e30f;
    #pragma unroll
    for (int k = 0; k < KK; ++k) { m0 = fmaxf(m0, lg[k].x); m1 = fmaxf(m1, lg[k].y); }
    float s0 = 0.f, s1 = 0.f;
    #pragma unroll
    for (int k = 0; k < KK; ++k) {
        lg[k].x = __expf(lg[k].x - m0); s0 += lg[k].x;
        lg[k].y = __expf(lg[k].y - m1); s1 += lg[k].y;
    }
    float i0 = 1.f / s0, i1 = 1.f / s1;
    #pragma unroll
    for (int k = 0; k < KK; ++k) { lg[k].x *= i0; lg[k].y *= i1; }

    int colg = 2 * pp2 - 2;
    int coff[3]; float cmask[3];
    #pragma unroll
    for (int jx = 0; jx < 3; ++jx) {
        int cg = colg + 2 * jx;
        cmask[jx] = (cg >= 0 && cg <= WW - 2) ? 1.f : 0.f;
        coff[jx]  = min(max(cg, 0), WW - 2);
    }
    int yoff[5]; float msk[15];
    #pragma unroll
    for (int di = 0; di < 5; ++di) {
        int y = h + di - 2;
        float rm = (y >= 0 && y < HH) ? 1.f : 0.f;
        yoff[di] = min(max(y, 0), HH - 1) * WW;
        #pragma unroll
        for (int jx = 0; jx < 3; ++jx) msk[di * 3 + jx] = rm * cmask[jx];
    }

    #pragma unroll 2
    for (int i8 = 0; i8 < 8; ++i8) {
        int c = i8 * 16 + cw;
        const float* xc = xb + (size_t)c * (HH * WW);
        float2 xv[15];
        #pragma unroll
        for (int di = 0; di < 5; ++di)
            #pragma unroll
            for (int jx = 0; jx < 3; ++jx) {
                float2 v = *(const float2*)(xc + yoff[di] + coff[jx]);
                float mm = msk[di * 3 + jx];
                xv[di * 3 + jx] = make_float2(v.x * mm, v.y * mm);
            }
        float t0 = 0.f, t1 = 0.f;
        #pragma unroll
        for (int di = 0; di < 5; ++di) {
            float2 x01 = xv[di * 3 + 0];
            float2 x23 = xv[di * 3 + 1];
            float2 x45 = xv[di * 3 + 2];
            t0 += lg[di*5+0].x * x01.x + lg[di*5+1].x * x01.y
                + lg[di*5+2].x * x23.x + lg[di*5+3].x * x23.y
                + lg[di*5+4].x * x45.x;
            t1 += lg[di*5+0].y * x01.y + lg[di*5+1].y * x23.x
                + lg[di*5+2].y * x23.y + lg[di*5+3].y * x45.x
                + lg[di*5+4].y * x45.y;
        }
        sKT[(2 * pp2) * 136 + c]     = f32_to_bf16(t0);
        sKT[(2 * pp2 + 1) * 136 + c] = f32_to_bf16(t1);
    }
    __syncthreads();

    // ---- MFMA2: C[o][px] = sum_c W2s[o][c] * s[c][px] ----
    floatx4 am[4] = {{0.f,0.f,0.f,0.f},{0.f,0.f,0.f,0.f},
                     {0.f,0.f,0.f,0.f},{0.f,0.f,0.f,0.f}};
    #pragma unroll
    for (int ks = 0; ks < 4; ++ks) {
        short8 af = *(const short8*)&w2o[(size_t)(16*wv + fpx) * CC + ks*32 + quad*8];
        #pragma unroll
        for (int nt = 0; nt < 4; ++nt) {
            short8 bf = *(const short8*)&sKT[(16*nt + fpx) * 136 + ks*32 + quad*8];
            am[nt] = __builtin_amdgcn_mfma_f32_16x16x32_bf16(af, bf, am[nt], 0, 0, 0);
        }
    }

    // ---- epilogue: D[row=quad*4+reg][col=fpx] + b2, 2x2-replicated write ----
    float* ob = out + (size_t)b * OUTC * (4 * HH * WW);
    int y0 = 2 * h;
    #pragma unroll
    for (int nt = 0; nt < 4; ++nt) {
        #pragma unroll
        for (int reg = 0; reg < 4; ++reg) {
            int o   = 16*wv + quad*4 + reg;
            int pxo = 16*nt + fpx;
            float v = am[nt][reg] + b2[o];
            float2 v2 = make_float2(v, v);
            float* r0p = ob + ((size_t)o * (2*HH) + y0) * (2*WW) + 2*pxo;
            *(float2*)(r0p)        = v2;
            *(float2*)(r0p + 2*WW) = v2;
        }
    }
}

// ---------------------------------------------------------------------------
extern "C" void kernel_launch(void* const* d_in, const int* in_sizes, int n_in,
                              void* d_out, int out_size, void* d_ws, size_t ws_size,
                              hipStream_t stream) {
    const float* x  = (const float*)d_in[0];
    const float* w1 = (const float*)d_in[1];
    const float* b1 = (const float*)d_in[2];
    const float* w2 = (const float*)d_in[3];
    const float* b2 = (const float*)d_in[4];
    float* out = (float*)d_out;

    unsigned short* w2o = (unsigned short*)d_ws;               // 32 KB
    unsigned short* w1f = w2o + (size_t)OUTC * CC;             // 147.5 KB

    prep_kernel<<<(16384 + 73728) / 256, 256, 0, stream>>>(w2, w1, w2o, w1f);
    fused_kernel<<<BB * HH, 512, 0, stream>>>(x, w1f, w2o, b1, b2, out);
}